// Round 2
// baseline (234.021 us; speedup 1.0000x reference)
//
#include <hip/hip_runtime.h>

// MultiHeadAttention (SAGAN reshape), B=C=1, T=3072, D=1024, H=16, head-dim 64.
// cvt(fp32->fp16) -> QKV GEMM (2-phase pipelined, fp16 MFMA)
//   -> repack K,V per-head (K pre-scaled by log2e)
//   -> flash attn: wave-split-j, in-register P (16x16x16 PV), deferred max,
//      swizzled LDS K/V, 2-phase staged
//   -> epilogue: transpose + gamma*out + residual.

typedef _Float16 v8h __attribute__((ext_vector_type(8)));
typedef _Float16 v4h __attribute__((ext_vector_type(4)));
typedef float    v4f __attribute__((ext_vector_type(4)));

#define TSEQ 3072
#define DM   1024
#define NH   16
#define XD   64
#define LOG2E 1.44269504f

__device__ __forceinline__ void async_load16(const void* g, void* l) {
  __builtin_amdgcn_global_load_lds(
      (const __attribute__((address_space(1))) unsigned int*)g,
      (__attribute__((address_space(3))) unsigned int*)l,
      16, 0, 0);
}

__device__ __forceinline__ float fexp2(float x) {
  float r; asm("v_exp_f32 %0, %1" : "=v"(r) : "v"(x)); return r;
}
__device__ __forceinline__ float flog2(float x) {
  float r; asm("v_log_f32 %0, %1" : "=v"(r) : "v"(x)); return r;
}

// ---------------- kernel 0: fp32 -> fp16 conversion -------------------------
extern "C" __global__ __launch_bounds__(256) void cvt_kernel(
    const float* __restrict__ x, const float* __restrict__ wq,
    const float* __restrict__ wk, const float* __restrict__ wv,
    _Float16* __restrict__ xb, _Float16* __restrict__ wb)
{
  const int NX4 = (TSEQ * DM) / 4;
  const int NT  = NX4 * 2;
  for (int i = blockIdx.x * blockDim.x + threadIdx.x; i < NT;
       i += gridDim.x * blockDim.x) {
    float4 v;
    _Float16* dst;
    if (i < NX4) {
      v = ((const float4*)x)[i];
      dst = xb + (size_t)i * 4;
    } else {
      const int j = i - NX4;
      const int n = j >> 8;
      if (n < 1024)      v = ((const float4*)wq)[j];
      else if (n < 2048) v = ((const float4*)wk)[j - 262144];
      else               v = ((const float4*)wv)[j - 524288];
      dst = wb + (size_t)j * 4;
    }
    v4h h;
    h[0] = (_Float16)v.x; h[1] = (_Float16)v.y;
    h[2] = (_Float16)v.z; h[3] = (_Float16)v.w;
    *(v4h*)dst = h;
  }
}

// ---------------- kernel 1: fused QKV GEMM (2-phase pipelined) --------------
extern "C" __global__ __launch_bounds__(256) void qkv_gemm_kernel(
    const _Float16* __restrict__ xb, const _Float16* __restrict__ wb,
    const float* __restrict__ bq, const float* __restrict__ bk,
    const float* __restrict__ bv,
    _Float16* __restrict__ qlin, _Float16* __restrict__ klin,
    _Float16* __restrict__ vlin)
{
  __shared__ _Float16 As[2][128 * 32];
  __shared__ _Float16 Bs[2][128 * 32];
  const int tid = threadIdx.x;
  const int w = tid >> 6, l = tid & 63;
  const int li = l & 15, lg = l >> 4;
  const int wm = w >> 1, wn = w & 1;
  const int bid = blockIdx.x;                 // 576 = 72*8, bijective XCD swz
  const int swz = (bid & 7) * 72 + (bid >> 3);
  const int m0 = (swz / 24) * 128, n0 = (swz % 24) * 128;
  v4f acc[4][4] = {};
  const int srow = l >> 2;
  const int scol = (l & 3) * 8;

  auto stage = [&](int buf, int k0) {
#pragma unroll
    for (int c = 0; c < 2; ++c) {
      const int rbase = c * 64 + w * 16;
      async_load16(xb + (size_t)(m0 + rbase + srow) * DM + k0 + scol,
                   &As[buf][rbase * 32]);
      async_load16(wb + (size_t)(n0 + rbase + srow) * DM + k0 + scol,
                   &Bs[buf][rbase * 32]);
    }
  };

  stage(0, 0);
  __syncthreads();
  for (int kt = 0; kt < DM / 32; ++kt) {
    const int buf = kt & 1;
    if (kt + 1 < DM / 32) stage(buf ^ 1, (kt + 1) * 32);
    v8h af[4], bf[4];
#pragma unroll
    for (int mi = 0; mi < 4; ++mi)
      af[mi] = *(const v8h*)&As[buf][(wm * 64 + mi * 16 + li) * 32 + lg * 8];
#pragma unroll
    for (int ni = 0; ni < 4; ++ni)
      bf[ni] = *(const v8h*)&Bs[buf][(wn * 64 + ni * 16 + li) * 32 + lg * 8];
#pragma unroll
    for (int mi = 0; mi < 4; ++mi)
#pragma unroll
      for (int ni = 0; ni < 4; ++ni)
        acc[mi][ni] = __builtin_amdgcn_mfma_f32_16x16x32_f16(
            af[mi], bf[ni], acc[mi][ni], 0, 0, 0);
    __syncthreads();
  }
  const int which = n0 >> 10;
  const int ebase = n0 & 1023;
  const float* bias = which == 0 ? bq : (which == 1 ? bk : bv);
  _Float16* outp = which == 0 ? qlin : (which == 1 ? klin : vlin);
#pragma unroll
  for (int mi = 0; mi < 4; ++mi)
#pragma unroll
    for (int r = 0; r < 4; ++r) {
      const int t = m0 + wm * 64 + mi * 16 + lg * 4 + r;
#pragma unroll
      for (int ni = 0; ni < 4; ++ni) {
        const int e = ebase + wn * 64 + ni * 16 + li;
        outp[(size_t)t * DM + e] = (_Float16)(acc[mi][ni][r] + bias[e]);
      }
    }
}

// ---------------- kernel 2: per-head repack (K scaled by log2e, + V) --------
// kh[h][j][x] = log2e * klin[t][e] ; vt[h][x][j] = vlin[t][e]
// with t = x*48 + j/64, e = (j%64)*16 + h.
extern "C" __global__ __launch_bounds__(256) void repack_kernel(
    const _Float16* __restrict__ klin, const _Float16* __restrict__ vlin,
    _Float16* __restrict__ kh, _Float16* __restrict__ vt)
{
  const int NE = NH * TSEQ * XD;   // 3145728
  for (int g = blockIdx.x * blockDim.x + threadIdx.x; g < 2 * NE;
       g += gridDim.x * blockDim.x) {
    if (g < NE) {
      const int xx = g & 63;
      const int rest = g >> 6;           // h*3072 + j
      const int h = rest / TSEQ;
      const int j = rest - h * TSEQ;
      const int t = xx * 48 + (j >> 6);
      const int e = ((j & 63) << 4) + h;
      kh[g] = (_Float16)((float)klin[t * DM + e] * LOG2E);
    } else {
      const int o = g - NE;
      const int j = o % TSEQ;
      const int rest = o / TSEQ;         // h*64 + x
      const int xx = rest & 63;
      const int h = rest >> 6;
      const int t = xx * 48 + (j >> 6);
      const int e = ((j & 63) << 4) + h;
      vt[o] = vlin[t * DM + e];
    }
  }
}

// ---------------- kernel 3: flash attention ---------------------------------
// 4 waves; each wave owns a 16-j slice of each 64-j tile, for all 64 Q rows.
// QK^T: mfma_16x16x32(A=K-slice, B=Q) -> E^T[j=lg*4+r][i=ct*16+li]  (log2 dom.)
// PV:   mfma_16x16x16(A=V^T, B=P in-register)  -- P layout matches B exactly.
// Deferred max: m2 init 24 nats (*log2e), per-lane guard, rare rescale.
// K/V LDS tiles XOR-swizzled at 16B granule via pre-swizzled global source.
extern "C" __global__ __launch_bounds__(256) void attn_kernel(
    const _Float16* __restrict__ qlin, const _Float16* __restrict__ kh,
    const _Float16* __restrict__ vt, _Float16* __restrict__ pOut)
{
  __shared__ _Float16 SH[16384];   // [buf][K|V][64*64]; reused for merge
  __shared__ float sml[4][64];
  const int tid = threadIdx.x;
  const int w = tid >> 6, l = tid & 63;
  const int li = l & 15, lg = l >> 4;
  const int head = blockIdx.y;
  const int i0 = blockIdx.x * 64;
  const size_t hb = (size_t)head * TSEQ * XD;

  // Q gather straight from qlin: qf[ct][xk][e] = Q[i0+ct*16+li][xk*32+lg*8+e]
  v8h qf[4][2];
#pragma unroll
  for (int ct = 0; ct < 4; ++ct) {
    const int i = i0 + ct * 16 + li;
    const int tbase = i >> 6;
    const int ecol = ((i & 63) << 4) + head;
#pragma unroll
    for (int xk = 0; xk < 2; ++xk)
#pragma unroll
      for (int e = 0; e < 8; ++e) {
        const int x = xk * 32 + lg * 8 + e;
        qf[ct][xk][e] = qlin[(size_t)(x * 48 + tbase) * DM + ecol];
      }
  }

  v4f oacc[4][4] = {};            // [mi][ct]: o^T[x=mi*16+lg*4+r][i=ct*16+li]
  float m2[4], l4[4];
#pragma unroll
  for (int ct = 0; ct < 4; ++ct) { m2[ct] = 24.0f * LOG2E; l4[ct] = 0.0f; }

  const int r8 = l >> 3, c8 = l & 7;

  auto stage = [&](int buf, int j0) {
#pragma unroll
    for (int s = 0; s < 2; ++s) {
      const int n = w * 2 + s;
      const int row = n * 8 + r8;
      async_load16(kh + hb + (size_t)(j0 + row) * XD + ((c8 ^ (row & 7)) * 8),
                   SH + buf * 8192 + n * 512);
      async_load16(vt + hb + (size_t)row * TSEQ + j0 + ((c8 ^ (row & 7)) * 8),
                   SH + buf * 8192 + 4096 + n * 512);
    }
  };

  stage(0, 0);
  __syncthreads();

  const int krow = w * 16 + li;
  const int kc0 = ((0 + lg) ^ (krow & 7)) * 8;
  const int kc1 = ((4 + lg) ^ (krow & 7)) * 8;

  for (int it = 0; it < TSEQ / 64; ++it) {
    const int buf = it & 1;
    if (it + 1 < TSEQ / 64) stage(buf ^ 1, (it + 1) * 64);
    const _Float16* Kc = SH + buf * 8192;
    const _Float16* Vc = SH + buf * 8192 + 4096;

    const v8h kf0 = *(const v8h*)&Kc[krow * 64 + kc0];
    const v8h kf1 = *(const v8h*)&Kc[krow * 64 + kc1];
    v4f e4[4];
#pragma unroll
    for (int ct = 0; ct < 4; ++ct) {
      v4f a = {};
      a = __builtin_amdgcn_mfma_f32_16x16x32_f16(kf0, qf[ct][0], a, 0, 0, 0);
      a = __builtin_amdgcn_mfma_f32_16x16x32_f16(kf1, qf[ct][1], a, 0, 0, 0);
      e4[ct] = a;
    }
    // speculative p = 2^(e - m2)  (no cross-lane dependency)
    float p[4][4];
#pragma unroll
    for (int ct = 0; ct < 4; ++ct)
#pragma unroll
      for (int r = 0; r < 4; ++r) p[ct][r] = fexp2(e4[ct][r] - m2[ct]);
    // guard (conservative): max over all 16 vs min m2
    float gmx = fmaxf(fmaxf(fmaxf(e4[0][0], e4[0][1]), fmaxf(e4[0][2], e4[0][3])),
                      fmaxf(fmaxf(e4[1][0], e4[1][1]), fmaxf(e4[1][2], e4[1][3])));
    gmx = fmaxf(gmx,
          fmaxf(fmaxf(fmaxf(e4[2][0], e4[2][1]), fmaxf(e4[2][2], e4[2][3])),
                fmaxf(fmaxf(e4[3][0], e4[3][1]), fmaxf(e4[3][2], e4[3][3]))));
    const float mmn = fminf(fminf(m2[0], m2[1]), fminf(m2[2], m2[3]));
    if (__any(gmx > mmn + 11.5f)) {          // rare rescale path
#pragma unroll
      for (int ct = 0; ct < 4; ++ct) {
        float tm = fmaxf(fmaxf(e4[ct][0], e4[ct][1]), fmaxf(e4[ct][2], e4[ct][3]));
        tm = fmaxf(tm, __shfl_xor(tm, 16, 64));
        tm = fmaxf(tm, __shfl_xor(tm, 32, 64));
        if (tm > m2[ct]) {
          const float fs = fexp2(m2[ct] - tm);
#pragma unroll
          for (int r = 0; r < 4; ++r) p[ct][r] *= fs;
          l4[ct] *= fs;
#pragma unroll
          for (int mi = 0; mi < 4; ++mi) oacc[mi][ct] *= fs;
          m2[ct] = tm;
        }
      }
    }
    v4h pv[4];
#pragma unroll
    for (int ct = 0; ct < 4; ++ct) {
      l4[ct] += (p[ct][0] + p[ct][1]) + (p[ct][2] + p[ct][3]);
#pragma unroll
      for (int r = 0; r < 4; ++r) pv[ct][r] = (_Float16)p[ct][r];
    }
    // PV, P straight from registers
#pragma unroll
    for (int mi = 0; mi < 4; ++mi) {
      const int vrow = mi * 16 + li;
      const v4h vf = *(const v4h*)&Vc[vrow * 64 +
                        (((w * 2 + (lg >> 1)) ^ (vrow & 7)) * 8) + (lg & 1) * 4];
#pragma unroll
      for (int ct = 0; ct < 4; ++ct)
        oacc[mi][ct] = __builtin_amdgcn_mfma_f32_16x16x16f16(
            vf, pv[ct], oacc[mi][ct], 0, 0, 0);
    }
    __syncthreads();
  }

  // ---- cross-wave merge: o_n = o/l (fp16) + s = m2 + log2(l) per wave ----
  _Float16* on = SH;
#pragma unroll
  for (int ct = 0; ct < 4; ++ct) {
    float ls = l4[ct];
    ls += __shfl_xor(ls, 16, 64);
    ls += __shfl_xor(ls, 32, 64);
    const float inv = 1.0f / ls;
    if (lg == 0) sml[w][ct * 16 + li] = m2[ct] + flog2(ls);
#pragma unroll
    for (int mi = 0; mi < 4; ++mi) {
      v4h o4;
#pragma unroll
      for (int r = 0; r < 4; ++r) o4[r] = (_Float16)(oacc[mi][ct][r] * inv);
      *(v4h*)&on[w * 4096 + (ct * 16 + li) * 64 + mi * 16 + lg * 4] = o4;
    }
  }
  __syncthreads();
  {
    const int im = w * 16 + (l >> 2);
    const int xs = (l & 3) * 16;
    float s0 = sml[0][im], s1 = sml[1][im], s2 = sml[2][im], s3 = sml[3][im];
    const float M = fmaxf(fmaxf(s0, s1), fmaxf(s2, s3));
    float u[4];
    u[0] = fexp2(s0 - M); u[1] = fexp2(s1 - M);
    u[2] = fexp2(s2 - M); u[3] = fexp2(s3 - M);
    const float D = u[0] + u[1] + u[2] + u[3];
    float acc[16] = {};
#pragma unroll
    for (int sw = 0; sw < 4; ++sw) {
      const v8h a = *(const v8h*)&on[sw * 4096 + im * 64 + xs];
      const v8h b = *(const v8h*)&on[sw * 4096 + im * 64 + xs + 8];
#pragma unroll
      for (int e = 0; e < 8; ++e) {
        acc[e]     += u[sw] * (float)a[e];
        acc[8 + e] += u[sw] * (float)b[e];
      }
    }
    const float di = 1.0f / D;
    v8h r0, r1;
#pragma unroll
    for (int e = 0; e < 8; ++e) {
      r0[e] = (_Float16)(acc[e] * di);
      r1[e] = (_Float16)(acc[8 + e] * di);
    }
    _Float16* dst = pOut + (size_t)(i0 + im) * DM + head * 64 + xs;
    *(v8h*)dst = r0;
    *(v8h*)(dst + 8) = r1;
  }
}

// ---------------- kernel 4: epilogue (transpose + residual) -----------------
// out[t][d] = gamma * pO[t][h=d&15][x=d>>4] + x[t][d]
extern "C" __global__ __launch_bounds__(256) void epilogue_kernel(
    const _Float16* __restrict__ pO, const float* __restrict__ xin,
    const float* __restrict__ gscal, float* __restrict__ outp)
{
  __shared__ _Float16 po[8 * 1024];
  const int tid = threadIdx.x;
  const size_t t0 = (size_t)blockIdx.x * 8;
  {
    const _Float16* src = pO + t0 * DM + tid * 32;
    v8h* d = (v8h*)&po[tid * 32];
#pragma unroll
    for (int c = 0; c < 4; ++c) d[c] = *(const v8h*)(src + c * 8);
  }
  __syncthreads();
  const float g = gscal[0];
  const int tr = tid >> 5;
  const int d0 = (tid & 31) * 32;
  const size_t rb = (t0 + tr) * DM + d0;
#pragma unroll
  for (int c4 = 0; c4 < 8; ++c4) {
    const float4 xi = *(const float4*)&xin[rb + c4 * 4];
    float4 r;
    r.x = g * (float)po[tr * 1024 + ((c4 * 4 + 0) & 15) * 64 + ((d0 + c4 * 4 + 0) >> 4)] + xi.x;
    r.y = g * (float)po[tr * 1024 + ((c4 * 4 + 1) & 15) * 64 + ((d0 + c4 * 4 + 1) >> 4)] + xi.y;
    r.z = g * (float)po[tr * 1024 + ((c4 * 4 + 2) & 15) * 64 + ((d0 + c4 * 4 + 2) >> 4)] + xi.z;
    r.w = g * (float)po[tr * 1024 + ((c4 * 4 + 3) & 15) * 64 + ((d0 + c4 * 4 + 3) >> 4)] + xi.w;
    *(float4*)&outp[rb + c4 * 4] = r;
  }
}

extern "C" void kernel_launch(void* const* d_in, const int* in_sizes, int n_in,
                              void* d_out, int out_size, void* d_ws, size_t ws_size,
                              hipStream_t stream)
{
  const float* x  = (const float*)d_in[0];
  const float* Wq = (const float*)d_in[1];
  const float* bq = (const float*)d_in[2];
  const float* Wk = (const float*)d_in[3];
  const float* bk = (const float*)d_in[4];
  const float* Wv = (const float*)d_in[5];
  const float* bv = (const float*)d_in[6];
  const float* gm = (const float*)d_in[7];
  float* outp = (float*)d_out;
  char* ws = (char*)d_ws;
  const size_t SZH = (size_t)TSEQ * DM * sizeof(_Float16);   // 6 MB
  _Float16* xb   = (_Float16*)(ws);                 // [0,6)
  _Float16* wb   = (_Float16*)(ws + SZH);           // [6,12)
  _Float16* qlin = (_Float16*)(ws + 2 * SZH);       // [12,18)
  _Float16* klin = (_Float16*)(ws + 3 * SZH);       // [18,24)
  _Float16* vlin = (_Float16*)(ws + 4 * SZH);       // [24,30)
  _Float16* khp  = (_Float16*)(ws + 5 * SZH);       // [30,36)
  _Float16* vtp  = (_Float16*)(ws + 6 * SZH);       // [36,42)
  _Float16* pO   = (_Float16*)(ws + 7 * SZH);       // [42,48)

  cvt_kernel<<<dim3(1024), dim3(256), 0, stream>>>(x, Wq, Wk, Wv, xb, wb);
  qkv_gemm_kernel<<<dim3(576), dim3(256), 0, stream>>>(xb, wb, bq, bk, bv,
                                                       qlin, klin, vlin);
  repack_kernel<<<dim3(2048), dim3(256), 0, stream>>>(klin, vlin, khp, vtp);
  attn_kernel<<<dim3(48, 16), dim3(256), 0, stream>>>(qlin, khp, vtp, pO);
  epilogue_kernel<<<dim3(384), dim3(256), 0, stream>>>(pO, x, gm, outp);
  (void)in_sizes; (void)n_in; (void)out_size; (void)ws_size;
}

// Round 3
// 152.716 us; speedup vs baseline: 1.5324x; 1.5324x over previous
//
#include <hip/hip_runtime.h>

// MultiHeadAttention (SAGAN reshape), B=C=1, T=3072, D=1024, H=16, head-dim 64.
// Round 3 = round-1 skeleton (verified 96.7us attn) + surgical upgrades:
//   - in-register P (PV via mfma_16x16x16, no P LDS round-trip)
//   - deferred-max softmax (no per-iter cross-lane reduce / rescale)
//   - K pre-scaled by log2e in repack (exp2 direct)
//   - direct fp16 output + cheap epilogue (round-2 verified)

typedef _Float16 v8h __attribute__((ext_vector_type(8)));
typedef _Float16 v4h __attribute__((ext_vector_type(4)));
typedef float    v4f __attribute__((ext_vector_type(4)));

#define TSEQ 3072
#define DM   1024
#define NH   16
#define XD   64
#define LOG2E 1.44269504f

__device__ __forceinline__ void async_load16(const void* g, void* l) {
  __builtin_amdgcn_global_load_lds(
      (const __attribute__((address_space(1))) unsigned int*)g,
      (__attribute__((address_space(3))) unsigned int*)l,
      16, 0, 0);
}

__device__ __forceinline__ float fexp2(float x) {
  float r; asm("v_exp_f32 %0, %1" : "=v"(r) : "v"(x)); return r;
}

// ---------------- kernel 0: fp32 -> fp16 conversion -------------------------
extern "C" __global__ __launch_bounds__(256) void cvt_kernel(
    const float* __restrict__ x, const float* __restrict__ wq,
    const float* __restrict__ wk, const float* __restrict__ wv,
    _Float16* __restrict__ xb, _Float16* __restrict__ wb)
{
  const int NX4 = (TSEQ * DM) / 4;
  const int NT  = NX4 * 2;
  for (int i = blockIdx.x * blockDim.x + threadIdx.x; i < NT;
       i += gridDim.x * blockDim.x) {
    float4 v;
    _Float16* dst;
    if (i < NX4) {
      v = ((const float4*)x)[i];
      dst = xb + (size_t)i * 4;
    } else {
      const int j = i - NX4;
      const int n = j >> 8;
      if (n < 1024)      v = ((const float4*)wq)[j];
      else if (n < 2048) v = ((const float4*)wk)[j - 262144];
      else               v = ((const float4*)wv)[j - 524288];
      dst = wb + (size_t)j * 4;
    }
    v4h h;
    h[0] = (_Float16)v.x; h[1] = (_Float16)v.y;
    h[2] = (_Float16)v.z; h[3] = (_Float16)v.w;
    *(v4h*)dst = h;
  }
}

// ---------------- kernel 1: fused QKV GEMM (round-1 body + XCD swizzle) -----
extern "C" __global__ __launch_bounds__(256) void qkv_gemm_kernel(
    const _Float16* __restrict__ xb, const _Float16* __restrict__ wb,
    const float* __restrict__ bq, const float* __restrict__ bk,
    const float* __restrict__ bv,
    _Float16* __restrict__ qlin, _Float16* __restrict__ klin,
    _Float16* __restrict__ vlin)
{
  __shared__ _Float16 As[128 * 32];
  __shared__ _Float16 Bs[128 * 32];
  const int tid = threadIdx.x;
  const int w = tid >> 6, l = tid & 63;
  const int li = l & 15, lg = l >> 4;
  const int wm = w >> 1, wn = w & 1;
  const int bid = blockIdx.x;                 // 576 = 72*8, bijective XCD swz
  const int swz = (bid & 7) * 72 + (bid >> 3);
  const int m0 = (swz / 24) * 128, n0 = (swz % 24) * 128;
  v4f acc[4][4] = {};
  const int srow = l >> 2;
  const int scol = (l & 3) * 8;
  for (int k0 = 0; k0 < DM; k0 += 32) {
#pragma unroll
    for (int c = 0; c < 2; ++c) {
      const int rbase = c * 64 + w * 16;
      async_load16(xb + (size_t)(m0 + rbase + srow) * DM + k0 + scol, &As[rbase * 32]);
      async_load16(wb + (size_t)(n0 + rbase + srow) * DM + k0 + scol, &Bs[rbase * 32]);
    }
    __syncthreads();
    v8h af[4], bf[4];
#pragma unroll
    for (int mi = 0; mi < 4; ++mi)
      af[mi] = *(const v8h*)&As[(wm * 64 + mi * 16 + li) * 32 + lg * 8];
#pragma unroll
    for (int ni = 0; ni < 4; ++ni)
      bf[ni] = *(const v8h*)&Bs[(wn * 64 + ni * 16 + li) * 32 + lg * 8];
#pragma unroll
    for (int mi = 0; mi < 4; ++mi)
#pragma unroll
      for (int ni = 0; ni < 4; ++ni)
        acc[mi][ni] = __builtin_amdgcn_mfma_f32_16x16x32_f16(
            af[mi], bf[ni], acc[mi][ni], 0, 0, 0);
    __syncthreads();
  }
  const int which = n0 >> 10;
  const int ebase = n0 & 1023;
  const float* bias = which == 0 ? bq : (which == 1 ? bk : bv);
  _Float16* outp = which == 0 ? qlin : (which == 1 ? klin : vlin);
#pragma unroll
  for (int mi = 0; mi < 4; ++mi)
#pragma unroll
    for (int r = 0; r < 4; ++r) {
      const int t = m0 + wm * 64 + mi * 16 + lg * 4 + r;
#pragma unroll
      for (int ni = 0; ni < 4; ++ni) {
        const int e = ebase + wn * 64 + ni * 16 + li;
        outp[(size_t)t * DM + e] = (_Float16)(acc[mi][ni][r] + bias[e]);
      }
    }
}

// ---------------- kernel 2: per-head repack ---------------------------------
// qh[h][i][x] = qlin[t][e];  kh[h][j][x] = log2e*klin[t][e];  vt[h][x][j]
// with t = x*48 + i/64, e = (i%64)*16 + h.
extern "C" __global__ __launch_bounds__(256) void repack_kernel(
    const _Float16* __restrict__ qlin, const _Float16* __restrict__ klin,
    const _Float16* __restrict__ vlin,
    _Float16* __restrict__ qh, _Float16* __restrict__ kh,
    _Float16* __restrict__ vt)
{
  const int NE = NH * TSEQ * XD;   // 3145728
  for (int g = blockIdx.x * blockDim.x + threadIdx.x; g < 3 * NE;
       g += gridDim.x * blockDim.x) {
    if (g < 2 * NE) {
      const int gg = (g < NE) ? g : g - NE;
      const int xx = gg & 63;
      const int rest = gg >> 6;          // h*3072 + i
      const int h = rest / TSEQ;
      const int i = rest - h * TSEQ;
      const int t = xx * 48 + (i >> 6);
      const int e = ((i & 63) << 4) + h;
      if (g < NE) qh[gg] = qlin[t * DM + e];
      else        kh[gg] = (_Float16)((float)klin[t * DM + e] * LOG2E);
    } else {
      const int o = g - 2 * NE;
      const int j = o % TSEQ;
      const int rest = o / TSEQ;          // h*64 + x
      const int xx = rest & 63;
      const int h = rest >> 6;
      const int t = xx * 48 + (j >> 6);
      const int e = ((j & 63) << 4) + h;
      vt[o] = vlin[t * DM + e];
    }
  }
}

// ---------------- kernel 3: flash attention ---------------------------------
// Round-1 skeleton: 4 waves x 16 Q-rows, KVBLK=64, single-buffer, 2 barriers.
// QK^T swapped: e4[kt] = E^T[j=kt*16+lg*4+r][i=li]  (log2 domain, K prescaled)
// P in-register -> PV via mfma_16x16x16(A=V^T from LDS, B=P).
// Deferred max: per-row m2 (uniform across lg-group), rare rescale.
extern "C" __global__ __launch_bounds__(256) void attn_kernel(
    const _Float16* __restrict__ qh, const _Float16* __restrict__ kh,
    const _Float16* __restrict__ vt, _Float16* __restrict__ pOut)
{
  __shared__ _Float16 Ks[64 * 64];       // [j][x], 16B-slot swizzled
  __shared__ _Float16 Vs[64 * 64];       // [x][j], 16B-slot swizzled
  const int tid = threadIdx.x;
  const int w = tid >> 6, l = tid & 63;
  const int li = l & 15, lg = l >> 4;
  const int head = blockIdx.y;
  const int i0 = blockIdx.x * 64;
  const size_t hb = (size_t)head * TSEQ * XD;

  v8h qf0, qf1;
  {
    const _Float16* qrow = qh + hb + (size_t)(i0 + w * 16 + li) * XD;
    qf0 = *(const v8h*)(qrow + lg * 8);
    qf1 = *(const v8h*)(qrow + 32 + lg * 8);
  }
  float m2 = 24.0f * LOG2E;   // deferred-max init (log2 units)
  float l4 = 0.0f;
  v4f oacc[4] = {};
  const int r8 = l >> 3, c8 = l & 7;

  for (int j0 = 0; j0 < TSEQ; j0 += 64) {
    // stage K,V tile (4 waves x 2 chunks each; linear LDS dest, pre-swz src)
#pragma unroll
    for (int s = 0; s < 2; ++s) {
      const int n = w * 2 + s;
      const int row = n * 8 + r8;
      async_load16(kh + hb + (size_t)(j0 + row) * XD + ((c8 ^ (row & 7)) * 8),
                   Ks + n * 512);
      async_load16(vt + hb + (size_t)row * TSEQ + j0 + ((c8 ^ (row & 7)) * 8),
                   Vs + n * 512);
    }
    __syncthreads();

    // QK^T: e4[kt] = E^T[j=kt*16+lg*4+r][i=li]
    v4f e4[4];
#pragma unroll
    for (int kt = 0; kt < 4; ++kt) {
      const int krow = kt * 16 + li;
      const v8h kf0 = *(const v8h*)&Ks[krow * 64 + ((lg ^ (krow & 7)) * 8)];
      const v8h kf1 = *(const v8h*)&Ks[krow * 64 + (((4 + lg) ^ (krow & 7)) * 8)];
      v4f a = {};
      a = __builtin_amdgcn_mfma_f32_16x16x32_f16(kf0, qf0, a, 0, 0, 0);
      a = __builtin_amdgcn_mfma_f32_16x16x32_f16(kf1, qf1, a, 0, 0, 0);
      e4[kt] = a;
    }

    // speculative p = 2^(e - m2); common path has NO cross-lane ops
    float p[4][4];
#pragma unroll
    for (int kt = 0; kt < 4; ++kt)
#pragma unroll
      for (int r = 0; r < 4; ++r) p[kt][r] = fexp2(e4[kt][r] - m2);

    float lmax = fmaxf(fmaxf(fmaxf(e4[0][0], e4[0][1]), fmaxf(e4[0][2], e4[0][3])),
                       fmaxf(fmaxf(e4[1][0], e4[1][1]), fmaxf(e4[1][2], e4[1][3])));
    lmax = fmaxf(lmax,
           fmaxf(fmaxf(fmaxf(e4[2][0], e4[2][1]), fmaxf(e4[2][2], e4[2][3])),
                 fmaxf(fmaxf(e4[3][0], e4[3][1]), fmaxf(e4[3][2], e4[3][3]))));
    if (__any(lmax > m2 + 11.5f)) {          // rare rescale path
      float rm = lmax;
      rm = fmaxf(rm, __shfl_xor(rm, 16, 64));
      rm = fmaxf(rm, __shfl_xor(rm, 32, 64));   // row max (lg-group)
      const float fs = (rm > m2) ? fexp2(m2 - rm) : 1.0f;
#pragma unroll
      for (int kt = 0; kt < 4; ++kt)
#pragma unroll
        for (int r = 0; r < 4; ++r) p[kt][r] *= fs;
      l4 *= fs;
#pragma unroll
      for (int mi = 0; mi < 4; ++mi) oacc[mi] *= fs;
      m2 = fmaxf(m2, rm);
    }

    v4h pv[4];
#pragma unroll
    for (int kt = 0; kt < 4; ++kt)
#pragma unroll
      for (int r = 0; r < 4; ++r) pv[kt][r] = (_Float16)p[kt][r];
    l4 += ((p[0][0] + p[0][1]) + (p[0][2] + p[0][3]))
        + ((p[1][0] + p[1][1]) + (p[1][2] + p[1][3]))
        + ((p[2][0] + p[2][1]) + (p[2][2] + p[2][3]))
        + ((p[3][0] + p[3][1]) + (p[3][2] + p[3][3]));

    // PV: oacc[mi] = o^T[x=mi*16+lg*4+r][i=li], P straight from registers
#pragma unroll
    for (int mi = 0; mi < 4; ++mi) {
      const int vrow = mi * 16 + li;
      const int vb = vrow * 64 + (lg & 1) * 4;
      v4f a = oacc[mi];
#pragma unroll
      for (int kt = 0; kt < 4; ++kt) {
        const v4h vf = *(const v4h*)&Vs[vb + (((kt * 2 + (lg >> 1)) ^ (vrow & 7)) * 8)];
        a = __builtin_amdgcn_mfma_f32_16x16x16f16(vf, pv[kt], a, 0, 0, 0);
      }
      oacc[mi] = a;
    }
    __syncthreads();
  }

  float ls = l4;
  ls += __shfl_xor(ls, 16, 64);
  ls += __shfl_xor(ls, 32, 64);
  const float inv = 1.0f / ls;
  const int irow = i0 + w * 16 + li;
#pragma unroll
  for (int mi = 0; mi < 4; ++mi) {
    v4h o4;
#pragma unroll
    for (int r = 0; r < 4; ++r) o4[r] = (_Float16)(oacc[mi][r] * inv);
    *(v4h*)&pOut[(size_t)irow * DM + head * 64 + mi * 16 + lg * 4] = o4;
  }
}

// ---------------- kernel 4: epilogue (transpose + residual) -----------------
// out[t][d] = gamma * pO[t][h=d&15][x=d>>4] + x[t][d]
extern "C" __global__ __launch_bounds__(256) void epilogue_kernel(
    const _Float16* __restrict__ pO, const float* __restrict__ xin,
    const float* __restrict__ gscal, float* __restrict__ outp)
{
  __shared__ _Float16 po[8 * 1024];
  const int tid = threadIdx.x;
  const size_t t0 = (size_t)blockIdx.x * 8;
  {
    const _Float16* src = pO + t0 * DM + tid * 32;
    v8h* d = (v8h*)&po[tid * 32];
#pragma unroll
    for (int c = 0; c < 4; ++c) d[c] = *(const v8h*)(src + c * 8);
  }
  __syncthreads();
  const float g = gscal[0];
  const int tr = tid >> 5;
  const int d0 = (tid & 31) * 32;
  const size_t rb = (t0 + tr) * DM + d0;
#pragma unroll
  for (int c4 = 0; c4 < 8; ++c4) {
    const float4 xi = *(const float4*)&xin[rb + c4 * 4];
    float4 r;
    r.x = g * (float)po[tr * 1024 + ((c4 * 4 + 0) & 15) * 64 + ((d0 + c4 * 4 + 0) >> 4)] + xi.x;
    r.y = g * (float)po[tr * 1024 + ((c4 * 4 + 1) & 15) * 64 + ((d0 + c4 * 4 + 1) >> 4)] + xi.y;
    r.z = g * (float)po[tr * 1024 + ((c4 * 4 + 2) & 15) * 64 + ((d0 + c4 * 4 + 2) >> 4)] + xi.z;
    r.w = g * (float)po[tr * 1024 + ((c4 * 4 + 3) & 15) * 64 + ((d0 + c4 * 4 + 3) >> 4)] + xi.w;
    *(float4*)&outp[rb + c4 * 4] = r;
  }
}

extern "C" void kernel_launch(void* const* d_in, const int* in_sizes, int n_in,
                              void* d_out, int out_size, void* d_ws, size_t ws_size,
                              hipStream_t stream)
{
  const float* x  = (const float*)d_in[0];
  const float* Wq = (const float*)d_in[1];
  const float* bq = (const float*)d_in[2];
  const float* Wk = (const float*)d_in[3];
  const float* bk = (const float*)d_in[4];
  const float* Wv = (const float*)d_in[5];
  const float* bv = (const float*)d_in[6];
  const float* gm = (const float*)d_in[7];
  float* outp = (float*)d_out;
  char* ws = (char*)d_ws;
  const size_t SZH = (size_t)TSEQ * DM * sizeof(_Float16);   // 6 MB
  _Float16* xb   = (_Float16*)(ws);                 // [0,6)   dead after gemm
  _Float16* wb   = (_Float16*)(ws + SZH);           // [6,12)  dead after gemm
  _Float16* qlin = (_Float16*)(ws + 2 * SZH);       // [12,18)
  _Float16* klin = (_Float16*)(ws + 3 * SZH);       // [18,24)
  _Float16* vlin = (_Float16*)(ws + 4 * SZH);       // [24,30)
  _Float16* qhp  = (_Float16*)(ws + 5 * SZH);       // [30,36)
  _Float16* khp  = (_Float16*)(ws + 6 * SZH);       // [36,42)
  _Float16* vtp  = (_Float16*)(ws + 7 * SZH);       // [42,48)
  _Float16* pO   = (_Float16*)(ws);                 // reuses [0,6) (xb dead)

  cvt_kernel<<<dim3(1024), dim3(256), 0, stream>>>(x, Wq, Wk, Wv, xb, wb);
  qkv_gemm_kernel<<<dim3(576), dim3(256), 0, stream>>>(xb, wb, bq, bk, bv,
                                                       qlin, klin, vlin);
  repack_kernel<<<dim3(4096), dim3(256), 0, stream>>>(qlin, klin, vlin,
                                                      qhp, khp, vtp);
  attn_kernel<<<dim3(48, 16), dim3(256), 0, stream>>>(qhp, khp, vtp, pO);
  epilogue_kernel<<<dim3(384), dim3(256), 0, stream>>>(pO, x, gm, outp);
  (void)in_sizes; (void)n_in; (void)out_size; (void)ws_size;
}